// Round 2
// baseline (21032.745 us; speedup 1.0000x reference)
//
#include <hip/hip_runtime.h>

// GRU decoder: B=16, S=2048, H=1024.
// Phase 1: xg = h_enc @ W_ih^T + b_ih  (MFMA bf16 GEMM, 32768x1024x3072)
// Phase 2: persistent-WG sequential scan, W_hh slices held in registers.
//   Cross-WG h broadcast via relaxed agent-scope atomics (sc0/sc1, straight to
//   Infinity Cache) — NO fence builtins (agent fences emit L2 wb/inv each step,
//   the R1 9.7us/step killer). Barrier = monotone atomic counter + s_waitcnt(0).

#define Bz 16
#define Sz 2048
#define Hz 1024
#define N3 3072
#define NWG 64          // scan workgroups (16 j-columns each)

typedef __bf16 bf16x8 __attribute__((ext_vector_type(8)));
typedef unsigned short ushort8 __attribute__((ext_vector_type(8)));
typedef float f32x4 __attribute__((ext_vector_type(4)));

__device__ __forceinline__ unsigned short f2bf(float f) {
    unsigned u = __float_as_uint(f);
    u += 0x7FFFu + ((u >> 16) & 1u);        // RNE
    return (unsigned short)(u >> 16);
}
__device__ __forceinline__ float bf2f(unsigned short s) {
    return __uint_as_float(((unsigned)s) << 16);
}
__device__ __forceinline__ ushort8 cvt8(float4 a, float4 b) {
    ushort8 v;
    v[0]=f2bf(a.x); v[1]=f2bf(a.y); v[2]=f2bf(a.z); v[3]=f2bf(a.w);
    v[4]=f2bf(b.x); v[5]=f2bf(b.y); v[6]=f2bf(b.z); v[7]=f2bf(b.w);
    return v;
}
__device__ __forceinline__ f32x4 mfma16(ushort8 a, ushort8 b, f32x4 c) {
    return __builtin_amdgcn_mfma_f32_16x16x32_bf16(
        __builtin_bit_cast(bf16x8, a), __builtin_bit_cast(bf16x8, b), c, 0, 0, 0);
}
__device__ __forceinline__ float sigm(float x) { return 1.0f / (1.0f + __expf(-x)); }

// ---------------- Phase 1: xg GEMM ----------------
__global__ __launch_bounds__(256) void xgemm(
        const float* __restrict__ A, const float* __restrict__ Wih,
        const float* __restrict__ b_ih, void* __restrict__ xg, int XF) {
    __shared__ unsigned short As[64 * 72];
    __shared__ unsigned short Bs[64 * 72];
    const int bid = blockIdx.x;
    const int n0 = (bid % 48) * 64;
    const int m0 = (bid / 48) * 64;
    const int tid = threadIdx.x;
    const int lane = tid & 63, w = tid >> 6;
    const int l16 = lane & 15, quad = lane >> 4;

    f32x4 acc[4] = {};
    for (int kb = 0; kb < Hz; kb += 64) {
        #pragma unroll
        for (int i = 0; i < 2; ++i) {
            int row = (tid >> 3) + i * 32;
            int kk = (tid & 7) * 8;
            const float4* ga = (const float4*)(A + (size_t)(m0 + row) * Hz + kb + kk);
            *(ushort8*)&As[row * 72 + kk] = cvt8(ga[0], ga[1]);
            const float4* gb = (const float4*)(Wih + (size_t)(n0 + row) * Hz + kb + kk);
            *(ushort8*)&Bs[row * 72 + kk] = cvt8(gb[0], gb[1]);
        }
        __syncthreads();
        const ushort8* arow = (const ushort8*)(As + (w * 16 + l16) * 72);
        ushort8 af0 = arow[quad], af1 = arow[4 + quad];
        #pragma unroll
        for (int ns = 0; ns < 4; ++ns) {
            const ushort8* brow = (const ushort8*)(Bs + (ns * 16 + l16) * 72);
            acc[ns] = mfma16(af0, brow[quad], acc[ns]);
            acc[ns] = mfma16(af1, brow[4 + quad], acc[ns]);
        }
        __syncthreads();
    }
    #pragma unroll
    for (int ns = 0; ns < 4; ++ns) {
        int col = n0 + ns * 16 + l16;
        float bi = b_ih[col];
        #pragma unroll
        for (int r = 0; r < 4; ++r) {
            size_t off = (size_t)(m0 + w * 16 + quad * 4 + r) * N3 + col;
            float v = acc[ns][r] + bi;
            if (XF) ((float*)xg)[off] = v;
            else    ((unsigned short*)xg)[off] = f2bf(v);
        }
    }
}

// ---------------- Phase 2: persistent scan ----------------
// hbufU layout (uint granularity, bf16 pairs): [slot][wg][b][jl2]
//   slot stride 8192 uints; per-WG slice = 128 contiguous uints (512 B).
__global__ __launch_bounds__(256, 1) void gru_scan(
        const float* __restrict__ Whh, const float* __restrict__ bhh,
        const void* __restrict__ xg, int XF,
        unsigned* __restrict__ hbufU,        // 2 x 8192 uints
        unsigned* __restrict__ bar,
        float* __restrict__ out) {
    __shared__ unsigned short h_s[16 * 1032];      // padded rows
    __shared__ float part[3 * 4 * 16 * 16];        // [g][w][m][n]
    __shared__ unsigned hs_new[128];               // packed h_{t+1} slice (bf16 pairs)
    const int tid = threadIdx.x;
    const int lane = tid & 63, w = tid >> 6;
    const int l16 = lane & 15, quad = lane >> 4;
    const int jb = blockIdx.x * 16;
    const int wK = w * 256;

    // Load W_hh B-fragments into registers (once).
    ushort8 wf[3][8];
    #pragma unroll
    for (int g = 0; g < 3; ++g) {
        const float* wrow = Whh + (size_t)(g * Hz + jb + l16) * Hz;
        #pragma unroll
        for (int kc = 0; kc < 8; ++kc) {
            const float4* p = (const float4*)(wrow + wK + kc * 32 + quad * 8);
            wf[g][kc] = cvt8(p[0], p[1]);
        }
    }

    // Per-thread gate identity: (b, j)
    const int b = tid >> 4, jl = tid & 15;
    const int j = jb + jl;
    const float bhr = bhh[j], bhz = bhh[Hz + j], bhn = bhh[2 * Hz + j];
    float hreg = 0.0f;

    // Prefetch xg for t=0
    float xr, xz, xn;
    {
        size_t xoff = (size_t)(b * Sz + 0) * N3 + j;
        if (XF) {
            const float* xp = (const float*)xg;
            xr = xp[xoff]; xz = xp[xoff + Hz]; xn = xp[xoff + 2 * Hz];
        } else {
            const unsigned short* xp = (const unsigned short*)xg;
            xr = bf2f(xp[xoff]); xz = bf2f(xp[xoff + Hz]); xn = bf2f(xp[xoff + 2 * Hz]);
        }
    }

    unsigned tgt = 0;
    for (int t = 0; t < Sz; ++t) {
        // ---- stage h_t -> LDS via agent-scope relaxed atomic loads (bypass L1/L2)
        const unsigned slot = (unsigned)(t & 1) * 8192u;
        #pragma unroll
        for (int i = 0; i < 32; ++i) {
            int u = tid + i * 256;
            unsigned v = __hip_atomic_load(hbufU + slot + u, __ATOMIC_RELAXED,
                                           __HIP_MEMORY_SCOPE_AGENT);
            int wg = u >> 7, r = u & 127, bb = r >> 3, jl2 = r & 7;
            *(unsigned*)(h_s + bb * 1032 + wg * 16 + jl2 * 2) = v;
        }
        __syncthreads();

        // ---- MFMA: D[m=batch][n=col], K-split across waves
        f32x4 a3[3] = {};
        const ushort8* hrow = (const ushort8*)(h_s + l16 * 1032);
        const int kbase = (wK >> 3) + quad;
        #pragma unroll
        for (int kc = 0; kc < 8; ++kc) {
            ushort8 af = hrow[kbase + kc * 4];
            a3[0] = mfma16(af, wf[0][kc], a3[0]);
            a3[1] = mfma16(af, wf[1][kc], a3[1]);
            a3[2] = mfma16(af, wf[2][kc], a3[2]);
        }
        #pragma unroll
        for (int g = 0; g < 3; ++g)
            #pragma unroll
            for (int r = 0; r < 4; ++r)
                part[((g * 4 + w) * 16 + (quad * 4 + r)) * 16 + l16] = a3[g][r];
        __syncthreads();

        // ---- gates for this thread's (b, j)
        float hr = 0, hz = 0, hn = 0;
        #pragma unroll
        for (int ww = 0; ww < 4; ++ww) {
            hr += part[((0 + ww) * 16 + b) * 16 + jl];
            hz += part[((4 + ww) * 16 + b) * 16 + jl];
            hn += part[((8 + ww) * 16 + b) * 16 + jl];
        }
        float r = sigm(xr + hr + bhr);
        float z = sigm(xz + hz + bhz);
        float n = tanhf(xn + r * (hn + bhn));
        float hnew = (1.0f - z) * n + z * hreg;
        hreg = hnew;
        out[(size_t)(b * Sz + t) * Hz + j] = hnew;           // plain store, no ordering needed
        ((unsigned short*)hs_new)[b * 16 + jl] = f2bf(hnew); // pack slice in LDS

        // ---- prefetch xg for t+1 (overlaps with barrier wait)
        {
            int t2 = (t + 1 < Sz) ? t + 1 : t;
            size_t xoff = (size_t)(b * Sz + t2) * N3 + j;
            if (XF) {
                const float* xp = (const float*)xg;
                xr = xp[xoff]; xz = xp[xoff + Hz]; xn = xp[xoff + 2 * Hz];
            } else {
                const unsigned short* xp = (const unsigned short*)xg;
                xr = bf2f(xp[xoff]); xz = bf2f(xp[xoff + Hz]); xn = bf2f(xp[xoff + 2 * Hz]);
            }
        }

        __syncthreads();   // hs_new complete
        // ---- publish h_{t+1} slice: 128 contiguous agent-scope atomic stores
        if (tid < 128) {
            unsigned nslot = (unsigned)((t + 1) & 1) * 8192u;
            __hip_atomic_store(hbufU + nslot + blockIdx.x * 128 + tid, hs_new[tid],
                               __ATOMIC_RELAXED, __HIP_MEMORY_SCOPE_AGENT);
        }
        // drain all vmem (sc1 store acks == visible at IC), then signal
        __builtin_amdgcn_s_waitcnt(0);
        tgt += NWG;
        if (tid == 0) {
            __hip_atomic_fetch_add(bar, 1u, __ATOMIC_RELAXED, __HIP_MEMORY_SCOPE_AGENT);
            while (__hip_atomic_load(bar, __ATOMIC_RELAXED, __HIP_MEMORY_SCOPE_AGENT) < tgt)
                __builtin_amdgcn_s_sleep(1);
        }
        __syncthreads();
    }
}

extern "C" void kernel_launch(void* const* d_in, const int* in_sizes, int n_in,
                              void* d_out, int out_size, void* d_ws, size_t ws_size,
                              hipStream_t stream) {
    const float* h_enc = (const float*)d_in[0];
    const float* W_ih  = (const float*)d_in[1];
    const float* W_hh  = (const float*)d_in[2];
    const float* b_ih  = (const float*)d_in[3];
    const float* b_hh  = (const float*)d_in[4];
    float* out = (float*)d_out;

    const size_t M = (size_t)Bz * Sz;              // 32768
    const size_t XG32 = M * N3 * 4;
    const size_t XG16 = M * N3 * 2;
    const int XF = (ws_size >= XG32 + (1 << 17)) ? 1 : 0;
    const size_t xgb = XF ? XG32 : XG16;

    char* base = (char*)d_ws;
    void* xg = (void*)base;
    unsigned* hbufU = (unsigned*)(base + xgb);
    unsigned* bar = (unsigned*)(base + xgb + 65536);

    // zero h0 double-buffer + barrier counter (runs every replay)
    hipMemsetAsync(base + xgb, 0, 65536 + 4096, stream);

    xgemm<<<dim3(512 * 48), dim3(256), 0, stream>>>(h_enc, W_ih, b_ih, xg, XF);
    gru_scan<<<dim3(NWG), dim3(256), 0, stream>>>(W_hh, b_hh, xg, XF, hbufU, bar, out);
}

// Round 3
// 11730.700 us; speedup vs baseline: 1.7930x; 1.7930x over previous
//
#include <hip/hip_runtime.h>
#include <hip/hip_fp16.h>

// GRU decoder: B=16, S=2048, H=1024.
// Phase 1: xg = h_enc @ W_ih^T + b_ih  (MFMA bf16 GEMM, out fp16 by default)
// Phase 2: persistent-WG scan with NO global barrier: h is broadcast through
//   per-step slots of (bf16<<16 | step_tag) words at IC scope. Consumers poll
//   tags directly (data-as-signal, single IC hop), re-polling stragglers only.

#define Bz 16
#define Sz 2048
#define Hz 1024
#define N3 3072
#define NWG 64          // scan workgroups (16 j-columns each)

typedef __bf16 bf16x8 __attribute__((ext_vector_type(8)));
typedef unsigned short ushort8 __attribute__((ext_vector_type(8)));
typedef float f32x4 __attribute__((ext_vector_type(4)));

__device__ __forceinline__ unsigned short f2bf(float f) {
    unsigned u = __float_as_uint(f);
    u += 0x7FFFu + ((u >> 16) & 1u);        // RNE
    return (unsigned short)(u >> 16);
}
__device__ __forceinline__ float bf2f(unsigned short s) {
    return __uint_as_float(((unsigned)s) << 16);
}
__device__ __forceinline__ ushort8 cvt8(float4 a, float4 b) {
    ushort8 v;
    v[0]=f2bf(a.x); v[1]=f2bf(a.y); v[2]=f2bf(a.z); v[3]=f2bf(a.w);
    v[4]=f2bf(b.x); v[5]=f2bf(b.y); v[6]=f2bf(b.z); v[7]=f2bf(b.w);
    return v;
}
__device__ __forceinline__ f32x4 mfma16(ushort8 a, ushort8 b, f32x4 c) {
    return __builtin_amdgcn_mfma_f32_16x16x32_bf16(
        __builtin_bit_cast(bf16x8, a), __builtin_bit_cast(bf16x8, b), c, 0, 0, 0);
}
__device__ __forceinline__ float sigm(float x) { return 1.0f / (1.0f + __expf(-x)); }

// ---------------- Phase 1: xg GEMM ----------------
__global__ __launch_bounds__(256) void xgemm(
        const float* __restrict__ A, const float* __restrict__ Wih,
        const float* __restrict__ b_ih, void* __restrict__ xg, int XF) {
    __shared__ unsigned short As[64 * 72];
    __shared__ unsigned short Bs[64 * 72];
    const int bid = blockIdx.x;
    const int n0 = (bid % 48) * 64;
    const int m0 = (bid / 48) * 64;
    const int tid = threadIdx.x;
    const int lane = tid & 63, w = tid >> 6;
    const int l16 = lane & 15, quad = lane >> 4;

    f32x4 acc[4] = {};
    for (int kb = 0; kb < Hz; kb += 64) {
        #pragma unroll
        for (int i = 0; i < 2; ++i) {
            int row = (tid >> 3) + i * 32;
            int kk = (tid & 7) * 8;
            const float4* ga = (const float4*)(A + (size_t)(m0 + row) * Hz + kb + kk);
            *(ushort8*)&As[row * 72 + kk] = cvt8(ga[0], ga[1]);
            const float4* gb = (const float4*)(Wih + (size_t)(n0 + row) * Hz + kb + kk);
            *(ushort8*)&Bs[row * 72 + kk] = cvt8(gb[0], gb[1]);
        }
        __syncthreads();
        const ushort8* arow = (const ushort8*)(As + (w * 16 + l16) * 72);
        ushort8 af0 = arow[quad], af1 = arow[4 + quad];
        #pragma unroll
        for (int ns = 0; ns < 4; ++ns) {
            const ushort8* brow = (const ushort8*)(Bs + (ns * 16 + l16) * 72);
            acc[ns] = mfma16(af0, brow[quad], acc[ns]);
            acc[ns] = mfma16(af1, brow[4 + quad], acc[ns]);
        }
        __syncthreads();
    }
    #pragma unroll
    for (int ns = 0; ns < 4; ++ns) {
        int col = n0 + ns * 16 + l16;
        float bi = b_ih[col];
        #pragma unroll
        for (int r = 0; r < 4; ++r) {
            size_t off = (size_t)(m0 + w * 16 + quad * 4 + r) * N3 + col;
            float v = acc[ns][r] + bi;
            if (XF) ((float*)xg)[off] = v;
            else    ((__half*)xg)[off] = __float2half(v);
        }
    }
}

// ---------------- Phase 2: persistent scan, barrier-free ----------------
// hbuf: Sz slots x 16384 words. slot[s] holds h_{s+1} as (bf16<<16 | (s+1)).
// Word index within slot: p*256 + b*16 + jl  (p = producer WG).
__global__ __launch_bounds__(256, 1) void gru_scan(
        const float* __restrict__ Whh, const float* __restrict__ bhh,
        const void* __restrict__ xg, int XF,
        unsigned* __restrict__ hbuf,
        float* __restrict__ out) {
    __shared__ unsigned short h_s[16 * 1032];      // [b][j], padded rows
    __shared__ float part[3 * 4 * 16 * 16];        // [g][w][m][n]
    const int tid = threadIdx.x;
    const int lane = tid & 63, w = tid >> 6;
    const int l16 = lane & 15, quad = lane >> 4;
    const int jb = blockIdx.x * 16;
    const int wK = w * 256;

    // W_hh B-fragments in registers (persistent).
    ushort8 wf[3][8];
    #pragma unroll
    for (int g = 0; g < 3; ++g) {
        const float* wrow = Whh + (size_t)(g * Hz + jb + l16) * Hz;
        #pragma unroll
        for (int kc = 0; kc < 8; ++kc) {
            const float4* p = (const float4*)(wrow + wK + kc * 32 + quad * 8);
            wf[g][kc] = cvt8(p[0], p[1]);
        }
    }

    const int b = tid >> 4, jl = tid & 15;
    const int j = jb + jl;
    const float bhr = bhh[j], bhz = bhh[Hz + j], bhn = bhh[2 * Hz + j];
    float hreg = 0.0f;

    // xg prefetch for t=0
    float xr, xz, xn;
    {
        size_t xoff = (size_t)(b * Sz) * N3 + j;
        if (XF) { const float* xp = (const float*)xg;
                  xr = xp[xoff]; xz = xp[xoff + Hz]; xn = xp[xoff + 2 * Hz]; }
        else    { const __half* xp = (const __half*)xg;
                  xr = __half2float(xp[xoff]); xz = __half2float(xp[xoff + Hz]);
                  xn = __half2float(xp[xoff + 2 * Hz]); }
    }

    for (int t = 0; t < Sz; ++t) {
        // ---- acquire h_t into LDS
        if (t == 0) {
            #pragma unroll
            for (int i = 0; i < 64; ++i)
                h_s[b * 1032 + i * 16 + jl] = 0;
        } else {
            const unsigned tagv = (unsigned)t;
            const unsigned* slot = hbuf + (size_t)(t - 1) * 16384u;
            unsigned hv[64];
            #pragma unroll
            for (int i = 0; i < 64; ++i)
                hv[i] = __hip_atomic_load(slot + (i << 8) + tid,
                                          __ATOMIC_RELAXED, __HIP_MEMORY_SCOPE_AGENT);
            #pragma unroll
            for (int i = 0; i < 64; ++i) {
                unsigned v = hv[i];
                while ((v & 0xFFFFu) != tagv)
                    v = __hip_atomic_load(slot + (i << 8) + tid,
                                          __ATOMIC_RELAXED, __HIP_MEMORY_SCOPE_AGENT);
                h_s[b * 1032 + i * 16 + jl] = (unsigned short)(v >> 16);
            }
        }
        __syncthreads();

        // ---- MFMA: D[m=batch][n=col], K-split across waves
        f32x4 a3[3] = {};
        const ushort8* hrow = (const ushort8*)(h_s + l16 * 1032);
        const int kbase = (wK >> 3) + quad;
        #pragma unroll
        for (int kc = 0; kc < 8; ++kc) {
            ushort8 af = hrow[kbase + kc * 4];
            a3[0] = mfma16(af, wf[0][kc], a3[0]);
            a3[1] = mfma16(af, wf[1][kc], a3[1]);
            a3[2] = mfma16(af, wf[2][kc], a3[2]);
        }
        #pragma unroll
        for (int g = 0; g < 3; ++g)
            #pragma unroll
            for (int r = 0; r < 4; ++r)
                part[((g * 4 + w) * 16 + (quad * 4 + r)) * 16 + l16] = a3[g][r];
        __syncthreads();

        // ---- gates for (b, j)
        float hr = 0, hz = 0, hn = 0;
        #pragma unroll
        for (int ww = 0; ww < 4; ++ww) {
            hr += part[((0 + ww) * 16 + b) * 16 + jl];
            hz += part[((4 + ww) * 16 + b) * 16 + jl];
            hn += part[((8 + ww) * 16 + b) * 16 + jl];
        }
        float r = sigm(xr + hr + bhr);
        float z = sigm(xz + hz + bhz);
        float n = tanhf(xn + r * (hn + bhn));
        float hnew = (1.0f - z) * n + z * hreg;
        hreg = hnew;

        // ---- publish h_{t+1} immediately (data-as-signal, tag = t+1)
        unsigned word = ((unsigned)f2bf(hnew) << 16) | (unsigned)(t + 1);
        __hip_atomic_store(hbuf + (size_t)t * 16384u + (blockIdx.x << 8) + tid, word,
                           __ATOMIC_RELAXED, __HIP_MEMORY_SCOPE_AGENT);
        out[(size_t)(b * Sz + t) * Hz + j] = hnew;

        // ---- prefetch xg for t+1 (hides under next poll)
        {
            int t2 = (t + 1 < Sz) ? t + 1 : t;
            size_t xoff = (size_t)(b * Sz + t2) * N3 + j;
            if (XF) { const float* xp = (const float*)xg;
                      xr = xp[xoff]; xz = xp[xoff + Hz]; xn = xp[xoff + 2 * Hz]; }
            else    { const __half* xp = (const __half*)xg;
                      xr = __half2float(xp[xoff]); xz = __half2float(xp[xoff + Hz]);
                      xn = __half2float(xp[xoff + 2 * Hz]); }
        }
    }
}

extern "C" void kernel_launch(void* const* d_in, const int* in_sizes, int n_in,
                              void* d_out, int out_size, void* d_ws, size_t ws_size,
                              hipStream_t stream) {
    const float* h_enc = (const float*)d_in[0];
    const float* W_ih  = (const float*)d_in[1];
    const float* W_hh  = (const float*)d_in[2];
    const float* b_ih  = (const float*)d_in[3];
    const float* b_hh  = (const float*)d_in[4];
    float* out = (float*)d_out;

    const size_t M = (size_t)Bz * Sz;                  // 32768
    const size_t XG32 = M * N3 * 4;                    // 402.7 MB
    const size_t XG16 = M * N3 * 2;                    // 201.3 MB
    const size_t HTAG = (size_t)Sz * 16384u * 4u;      // 134.2 MB
    const int XF = (ws_size >= XG32 + HTAG + (1 << 16)) ? 1 : 0;
    const size_t xgb = XF ? XG32 : XG16;

    char* base = (char*)d_ws;
    void* xg = (void*)base;
    unsigned* hbuf = (unsigned*)(base + xgb);

    // clear tags (poison 0xAAAA can't match, but first-launch ws is undefined)
    hipMemsetAsync(hbuf, 0, HTAG, stream);

    xgemm<<<dim3(512 * 48), dim3(256), 0, stream>>>(h_enc, W_ih, b_ih, xg, XF);
    gru_scan<<<dim3(NWG), dim3(256), 0, stream>>>(W_hh, b_hh, xg, XF, hbuf, out);
}